// Round 6
// baseline (612.344 us; speedup 1.0000x reference)
//
#include <hip/hip_runtime.h>
#include <hip/hip_bf16.h>
#include <math.h>

typedef unsigned short ushort;
typedef unsigned int uint;

// Sizes (fixed by the reference problem)
#define NV 200     // N nodes
#define DEG 199
#define HID 96
#define KG 20      // groups / one-hot width
#define MG 10      // group size
#define AJR 30
#define NH 4
#define HD 118     // HID + 2 + K
#define DM 472     // NH*HD
#define NN 40000   // N*N

// Workspace layout (float units).
#define WS_BASE   0
#define WS_H1     19200
#define WS_H2     38400
#define WS_HFULL  57600
#define WS_GMEAN  81200
#define WS_W0S    83560
#define WS_W1S    139256
#define WS_KHF    194952
#define WS_VHF    289352
#define WS_B1     383752  // after k_SC: reused for SCL (160000 floats)
#define WS_B2     478152
#define WS_SC1    572552
#define WS_SC2    732552
#define WS_Z      892552   // Z fp32: 4*224*472 = 422,912 floats
#define WS_ZB     1315464  // ZB bf16 frags: 458,752 ushorts = 229,376 floats
#define WS_M1     1544840
#define WS_M2     1545640
#define WS_E1     1546440  // 160,000 floats
#define WS_E2     1706440  // 160,000 floats
#define WS_V1B    1866440  // v1 bf16 frags: 23,040 ushorts = 11,520 floats

// Output layout (floats)
#define OFF_H   18880000
#define OFF_HF  18899200
#define OFF_Q   18922800

typedef __attribute__((ext_vector_type(8))) short short8v;
typedef __attribute__((ext_vector_type(4))) float float4v;

__device__ __forceinline__ float bf2f(uint u) {
  return __uint_as_float(u << 16);
}
__device__ __forceinline__ ushort f2bf(float f) {
  uint u = __float_as_uint(f);
  uint r = (u + 0x7fffu + ((u >> 16) & 1u)) >> 16;  // RNE
  return (ushort)r;
}
__device__ __forceinline__ uint packbf(float a, float b) {
  __hip_bfloat162 h2 = __float22bfloat162_rn(make_float2(a, b));
  union { __hip_bfloat162 h; uint u; } c;
  c.h = h2;
  return c.u;
}

// ---------------------------------------------------------------------------
// A: iteration-invariant part of the GCN update
// ---------------------------------------------------------------------------
__global__ __launch_bounds__(256) void k_base(
    const float* __restrict__ x, const float* __restrict__ dmat,
    const float* __restrict__ label,
    const float* __restrict__ l0w, const float* __restrict__ l0b,
    const float* __restrict__ l1w, const float* __restrict__ l1b,
    const float* __restrict__ l2b, const float* __restrict__ l3b,
    const float* __restrict__ l4w, const float* __restrict__ l4b,
    const float* __restrict__ l5w, const float* __restrict__ l5b,
    float* __restrict__ base) {
  int i = blockIdx.x; int t = threadIdx.x;
  int g = i / MG;
  __shared__ float sv[256];
  __shared__ float sn2[9];
  float v = -1.0f;
  if (t < DEG) {
    int u = (t < i) ? t : t + 1;
    if (u / MG != g) v = dmat[i * DEG + t];
  }
  sv[t] = v;
  __syncthreads();
  for (int k2 = 2; k2 <= 256; k2 <<= 1) {
    for (int jj = k2 >> 1; jj > 0; jj >>= 1) {
      int ixj = t ^ jj;
      if (ixj > t) {
        float a = sv[t], b = sv[ixj];
        bool sw = ((t & k2) == 0) ? (a < b) : (a > b);
        if (sw) { sv[t] = b; sv[ixj] = a; }
      }
      __syncthreads();
    }
  }
  if (t == 0) {
    float tmp[9];
    for (int q = 0; q < 9; q++) tmp[q] = dmat[i * DEG + MG * g + q];
    for (int a2 = 1; a2 < 9; a2++) {
      float key = tmp[a2]; int b2 = a2 - 1;
      while (b2 >= 0 && tmp[b2] < key) { tmp[b2 + 1] = tmp[b2]; b2--; }
      tmp[b2 + 1] = key;
    }
    for (int q = 0; q < 9; q++) sn2[q] = tmp[q];
  }
  __syncthreads();
  if (t < HID) {
    float acc = l0b[t] + l1b[t] + l2b[t] + l3b[t] + l4b[t] + l5b[t];
    acc += x[i * 2 + 0] * l0w[t] + x[i * 2 + 1] * l0w[HID + t];
    for (int k = 0; k < KG; k++) acc += label[i * KG + k] * l1w[k * HID + t];
    for (int q = 0; q < AJR; q++) acc += sv[q] * l4w[q * HID + t];
    for (int q = 0; q < 9; q++) acc += sn2[q] * l5w[q * HID + t];
    base[i * HID + t] = acc;
  }
}

// ---------------------------------------------------------------------------
// B: one GCN step
// ---------------------------------------------------------------------------
__global__ __launch_bounds__(192) void k_gcn(
    const float* __restrict__ hin, const float* __restrict__ base,
    const float* __restrict__ w, const float* __restrict__ l2w,
    const float* __restrict__ l3w, float* __restrict__ hout) {
  int i = blockIdx.x; int t = threadIdx.x;
  int g = i / MG;
  __shared__ float n1[HID], n2[HID];
  if (t < HID) {
    float acc = 0.f, wsum = 0.f;
    for (int j = 0; j < DEG; j++) {
      int u = (j < i) ? j : j + 1;
      if (u / MG != g) {
        float wj = w[i * DEG + j];
        acc += wj * hin[u * HID + t];
        wsum += wj;
      }
    }
    n1[t] = acc / wsum;
  } else if (t < 2 * HID) {
    int dd = t - HID;
    float acc = 0.f, wsum = 0.f;
    for (int u = MG * g; u < MG * g + MG; u++) {
      if (u == i) continue;
      int j = (u < i) ? u : u - 1;
      float wj = w[i * DEG + j];
      acc += wj * hin[u * HID + dd];
      wsum += wj;
    }
    n2[dd] = acc / wsum;
  }
  __syncthreads();
  if (t < HID) {
    float acc = base[i * HID + t];
    for (int dd = 0; dd < HID; dd++)
      acc += n1[dd] * l2w[dd * HID + t] + n2[dd] * l3w[dd * HID + t];
    hout[i * HID + t] = fmaxf(acc, 0.f);
  }
}

// ---------------------------------------------------------------------------
// C1: h_full assembly (+ h, h_full outputs)
// ---------------------------------------------------------------------------
__global__ __launch_bounds__(128) void k_hfull(
    const float* __restrict__ h, const float* __restrict__ x,
    const float* __restrict__ label, const int* __restrict__ remain_step,
    float* __restrict__ hfull, float* __restrict__ out_h,
    float* __restrict__ out_hf) {
  int i = blockIdx.x; int t = threadIdx.x;
  if (t < HD) {
    float v;
    if (t < HID) {
      int p = *remain_step;
      int t2 = t & ~1;
      float div = expf(-(float)t2 * (logf(10000.f) / (float)HID));
      float ang = (float)p * div;
      float pe = (t & 1) ? cosf(ang) : sinf(ang);
      float hv = h[i * HID + t];
      out_h[i * HID + t] = hv;
      v = hv + pe;
    } else if (t < HID + 2) {
      v = x[i * 2 + (t - HID)];
    } else {
      v = label[i * KG + (t - HID - 2)];
    }
    hfull[i * HD + t] = v;
    out_hf[i * HD + t] = v;
  }
}

// C2: group means of h_full
__global__ __launch_bounds__(128) void k_gmean(
    const float* __restrict__ hfull, float* __restrict__ gmean) {
  int g = blockIdx.x; int t = threadIdx.x;
  if (t < HD) {
    float s = 0.f;
    for (int q = 0; q < MG; q++) s += hfull[(g * MG + q) * HD + t];
    gmean[g * HD + t] = s * 0.1f;
  }
}

// D1: sum of the 4 118-row blocks of mha_w{0,1}
__global__ __launch_bounds__(256) void k_wsum(
    const float* __restrict__ w0, const float* __restrict__ w1,
    float* __restrict__ W0s, float* __restrict__ W1s) {
  int idx = blockIdx.x * blockDim.x + threadIdx.x;
  if (idx < HD * DM) {
    int dp = idx / DM, c = idx - dp * DM;
    W0s[idx] = w0[dp * DM + c] + w0[(HD + dp) * DM + c] +
               w0[(2 * HD + dp) * DM + c] + w0[(3 * HD + dp) * DM + c];
    W1s[idx] = w1[dp * DM + c] + w1[(HD + dp) * DM + c] +
               w1[(2 * HD + dp) * DM + c] + w1[(3 * HD + dp) * DM + c];
  }
}

// D2: khf / vhf
__global__ __launch_bounds__(256) void k_kv(
    const float* __restrict__ hfull, const float* __restrict__ W0s,
    const float* __restrict__ b0v, const float* __restrict__ W1s,
    const float* __restrict__ b1v, float* __restrict__ khf,
    float* __restrict__ vhf) {
  int i = blockIdx.x; int t = threadIdx.x;
  __shared__ float hr[HD];
  if (t < HD) hr[t] = hfull[i * HD + t];
  __syncthreads();
  for (int c = t; c < DM; c += 256) {
    float a0 = b0v[c], a1 = b1v[c];
    for (int dd = 0; dd < HD; dd++) {
      float hv = hr[dd];
      a0 += hv * W0s[dd * DM + c];
      a1 += hv * W1s[dd * DM + c];
    }
    khf[i * DM + c] = a0;
    vhf[i * DM + c] = a1;
  }
}

// D3: B1/B2 (query decomposition)
__global__ __launch_bounds__(256) void k_B(
    const float* __restrict__ hfull, const float* __restrict__ gmean,
    const float* __restrict__ w0, const float* __restrict__ b0v,
    float* __restrict__ B1, float* __restrict__ B2) {
  int i = blockIdx.x; int t = threadIdx.x; int g = i / MG;
  __shared__ float hr[HD], gr[HD];
  if (t < HD) { hr[t] = hfull[i * HD + t]; gr[t] = gmean[g * HD + t]; }
  __syncthreads();
  for (int c = t; c < DM; c += 256) {
    float a1 = 0.f, a2 = b0v[c];
    for (int dd = 0; dd < HD; dd++) {
      a1 += hr[dd] * w0[dd * DM + c] + gr[dd] * w0[(2 * HD + dd) * DM + c];
      a2 += hr[dd] * w0[(HD + dd) * DM + c] + gr[dd] * w0[(3 * HD + dd) * DM + c];
    }
    B1[i * DM + c] = a1;
    B2[i * DM + c] = a2;
  }
}

// D4: score components SC1/SC2, pre-scaled by (1/sqrt(HD))*log2(e)
__global__ __launch_bounds__(256) void k_SC(
    const float* __restrict__ B1, const float* __restrict__ B2,
    const float* __restrict__ khf, float* __restrict__ SC1,
    float* __restrict__ SC2) {
  int i = blockIdx.x; int t = threadIdx.x;
  const float scl = 1.4426950408889634f / sqrtf((float)HD);
  __shared__ float b1r[DM], b2r[DM];
  for (int c = t; c < DM; c += 256) { b1r[c] = B1[i * DM + c]; b2r[c] = B2[i * DM + c]; }
  __syncthreads();
  for (int p = t; p < NH * NV; p += 256) {
    int h = p / NV, k = p - h * NV;
    float s1a = 0.f, s2a = 0.f;
    for (int dd = 0; dd < HD; dd++) {
      float kv = khf[k * DM + h * HD + dd];
      s1a += b1r[h * HD + dd] * kv;
      s2a += b2r[h * HD + dd] * kv;
    }
    SC1[h * NN + i * NV + k] = s1a * scl;
    SC2[h * NN + i * NV + k] = s2a * scl;
  }
}

// D4b: row maxes m1[h,i] = max_k SC1[h,i,k], m2[h,i] = max_k SC2[h,i,k]
__global__ __launch_bounds__(64) void k_rowmax(
    const float* __restrict__ SC1, const float* __restrict__ SC2,
    float* __restrict__ M1, float* __restrict__ M2) {
  int i = blockIdx.x, h = blockIdx.y;
  int t = threadIdx.x;
  const float* p1 = SC1 + h * NN + i * NV;
  const float* p2 = SC2 + h * NN + i * NV;
  float m1 = -1e30f, m2 = -1e30f;
  for (int k = t; k < NV; k += 64) {
    m1 = fmaxf(m1, p1[k]);
    m2 = fmaxf(m2, p2[k]);
  }
#pragma unroll
  for (int off = 32; off > 0; off >>= 1) {
    m1 = fmaxf(m1, __shfl_xor(m1, off));
    m2 = fmaxf(m2, __shfl_xor(m2, off));
  }
  if (t == 0) { M1[h * NV + i] = m1; M2[h * NV + i] = m2; }
}

// D5: SCL[h][i][j] = exp2(m1_i + m2_j - C_ij)  (C = logsumexp in exp2 domain)
__global__ __launch_bounds__(256) void k_ml2(
    const float* __restrict__ SC1, const float* __restrict__ SC2,
    const float* __restrict__ M1, const float* __restrict__ M2,
    float* __restrict__ SCL) {
  int i = blockIdx.x, h = blockIdx.y;
  int t = threadIdx.x;
  __shared__ float s1s[224];
  for (int k = t; k < 224; k += 256)
    s1s[k] = (k < NV) ? SC1[h * NN + i * NV + k] : -1e30f;
  __syncthreads();
  float m1v = M1[h * NV + i];
  int l = t & 31;
  int g = t >> 5;
  const float* s2b = SC2 + h * NN;
  for (int it = 0; it < 25; ++it) {
    int j = it * 8 + g;
    const float* row = s2b + j * NV;
    float v[7];
#pragma unroll
    for (int e = 0; e < 7; ++e) {
      int k = l + 32 * e;
      v[e] = (k < NV) ? (s1s[k] + row[k]) : -1e30f;
    }
    float m = v[0];
#pragma unroll
    for (int e = 1; e < 7; ++e) m = fmaxf(m, v[e]);
#pragma unroll
    for (int off = 16; off > 0; off >>= 1) m = fmaxf(m, __shfl_xor(m, off, 32));
    float s = 0.f;
#pragma unroll
    for (int e = 0; e < 7; ++e) s += exp2f(v[e] - m);
#pragma unroll
    for (int off = 16; off > 0; off >>= 1) s += __shfl_xor(s, off, 32);
    if (l == 0)
      SCL[h * NN + i * NV + j] = exp2f(m1v + M2[h * NV + j] - m) / s;
  }
}

// D6: E1 = exp2(SC1 - m1), E2 = exp2(SC2 - m2)
__global__ __launch_bounds__(256) void k_exp(
    const float* __restrict__ SC1, const float* __restrict__ SC2,
    const float* __restrict__ M1, const float* __restrict__ M2,
    float* __restrict__ E1, float* __restrict__ E2) {
  int i = blockIdx.x, h = blockIdx.y;
  int t = threadIdx.x;
  if (t < NV) {
    size_t o = (size_t)h * NN + i * NV + t;
    E1[o] = exp2f(SC1[o] - M1[h * NV + i]);
    E2[o] = exp2f(SC2[o] - M2[h * NV + i]);
  }
}

// ---------------------------------------------------------------------------
// E1: Z[h][k][c] = sum_d vhf[k][h*HD+d] * w3[(h*HD+d)*DM + c]  (fp32)
// ---------------------------------------------------------------------------
__global__ __launch_bounds__(256) void k_Z(
    const float* __restrict__ vhf, const float* __restrict__ w3,
    float* __restrict__ Z) {
  int k = blockIdx.x, h = blockIdx.y;
  int t = threadIdx.x;
  __shared__ float vr[HD];
  if (t < HD) vr[t] = vhf[k * DM + h * HD + t];
  __syncthreads();
  for (int c = t; c < DM; c += 256) {
    float a = 0.f;
    for (int d = 0; d < HD; ++d) a += vr[d] * w3[(h * HD + d) * DM + c];
    Z[((size_t)h * 224 + k) * DM + c] = a;
  }
}

// E2: ZB = Z in MFMA B-fragment layout, bf16, zero-padded.
// frag f = (h*7+ks)*32 + dt; element lane*8+q:
//   k = ks*32 + (lane>>4)*8 + q, c = dt*16 + (lane&15)
__global__ __launch_bounds__(256) void k_ZB(
    const float* __restrict__ Z, ushort* __restrict__ ZB) {
  int idx = blockIdx.x * 256 + threadIdx.x;  // < 896*512 = 458752
  if (idx >= 896 * 512) return;
  int f = idx >> 9, e = idx & 511;
  int lane = e >> 3, q = e & 7;
  int dt = f & 31, hk = f >> 5;
  int ks = hk % 7, h = hk / 7;
  int k = ks * 32 + (lane >> 4) * 8 + q;
  int c = dt * 16 + (lane & 15);
  ushort v = 0;
  if (k < NV && c < DM) v = f2bf(Z[((size_t)h * 224 + k) * DM + c]);
  ZB[idx] = v;
}

// E3: V1B = v1w in MFMA B-fragment layout, bf16 (K padded 472->480, N=48)
// frag f = ks*3 + dt (ks 0..14, dt 0..2)
__global__ __launch_bounds__(256) void k_v1B(
    const float* __restrict__ v1w, ushort* __restrict__ V1B) {
  int idx = blockIdx.x * 256 + threadIdx.x;  // < 45*512 = 23040
  if (idx >= 45 * 512) return;
  int f = idx >> 9, e = idx & 511;
  int lane = e >> 3, q = e & 7;
  int dt = f % 3, ks = f / 3;
  int k = ks * 32 + (lane >> 4) * 8 + q;
  int c = dt * 16 + (lane & 15);
  ushort v = 0;
  if (k < DM) v = f2bf(v1w[k * 48 + c]);
  V1B[idx] = v;
}

// ---------------------------------------------------------------------------
// F: fused attention+output GEMM with product-form P:
// P[b=(i,j)][h,k] = E1[i,k]*E2[j,k]*SCL[i,j] + E1[j,k]*E2[i,k]*SCL[j,i]
// S = P @ Z + 2*b3.  128x256 tile, grid (2, 313); B direct from global ZB
// (fragment layout, L2-resident) -> no k-loop barriers, no LDS staging.
// ---------------------------------------------------------------------------
__global__ __launch_bounds__(256, 2) void k_sfused2(
    const float* __restrict__ E1, const float* __restrict__ E2,
    const float* __restrict__ SCL, const ushort* __restrict__ ZB,
    const float* __restrict__ b3, float* __restrict__ outS) {
  int t = threadIdx.x;
  int c0 = blockIdx.x * 256, b0 = blockIdx.y * 128;
  int lane = t & 63, wm = t >> 6;
  int frow = lane & 15, quad = lane >> 4;
  __shared__ __align__(16) float E1i_s[2][224];
  __shared__ __align__(16) float E2i_s[2][224];
  __shared__ float scij_s[128], scji_s[128];
  int i0 = b0 / NV;
  int i1 = (b0 + 127) / NV; if (i1 >= NV) i1 = NV - 1;
  int rr[2], jj[2], isel[2]; bool bval[2];
#pragma unroll
  for (int m = 0; m < 2; ++m) {
    rr[m] = wm * 32 + m * 16 + frow;
    int b = b0 + rr[m];
    bval[m] = (b < NN);
    int ii = bval[m] ? (b / NV) : 0;
    jj[m] = bval[m] ? (b - ii * NV) : 0;
    isel[m] = bval[m] ? (ii - i0) : 0;
  }
  float4v acc[2][16];
#pragma unroll
  for (int m = 0; m < 2; ++m)
#pragma unroll
    for (int n = 0; n < 16; ++n) acc[m][n] = (float4v)(0.f);
  int dtbase = c0 >> 4;

  for (int h = 0; h < NH; ++h) {
    __syncthreads();
    for (int e = t; e < 224; e += 256) {
      bool v = (e < NV);
      E1i_s[0][e] = v ? E1[h * NN + i0 * NV + e] : 0.f;
      E2i_s[0][e] = v ? E2[h * NN + i0 * NV + e] : 0.f;
      E1i_s[1][e] = v ? E1[h * NN + i1 * NV + e] : 0.f;
      E2i_s[1][e] = v ? E2[h * NN + i1 * NV + e] : 0.f;
    }
    for (int e = t; e < 128; e += 256) {
      int b = b0 + e;
      if (b < NN) {
        int ii = b / NV, jv = b - ii * NV;
        scij_s[e] = SCL[h * NN + b];
        scji_s[e] = SCL[h * NN + jv * NV + ii];
      } else {
        scij_s[e] = 0.f; scji_s[e] = 0.f;
      }
    }
    __syncthreads();
    float ci[2], cj[2];
    const float* pj1[2]; const float* pj2[2];
#pragma unroll
    for (int m = 0; m < 2; ++m) {
      ci[m] = scij_s[rr[m]];
      cj[m] = scji_s[rr[m]];
      pj1[m] = E1 + h * NN + jj[m] * NV;
      pj2[m] = E2 + h * NN + jj[m] * NV;
    }
    const ushort* zbh = ZB + ((size_t)(h * 7 * 32 + dtbase) << 9) + lane * 8;
    for (int ks = 0; ks < 7; ++ks) {
      int kb = ks * 32 + quad * 8;
      bool kvalid = (kb + 8 <= NV);
      union { uint4 q; short8v v; } af[2];
#pragma unroll
      for (int m = 0; m < 2; ++m) {
        if (bval[m] && kvalid) {
          float4 e2ja = *(const float4*)(pj2[m] + kb);
          float4 e2jb = *(const float4*)(pj2[m] + kb + 4);
          float4 e1ja = *(const float4*)(pj1[m] + kb);
          float4 e1jb = *(const float4*)(pj1[m] + kb + 4);
          float4 e1ia = *(const float4*)&E1i_s[isel[m]][kb];
          float4 e1ib = *(const float4*)&E1i_s[isel[m]][kb + 4];
          float4 e2ia = *(const float4*)&E2i_s[isel[m]][kb];
          float4 e2ib = *(const float4*)&E2i_s[isel[m]][kb + 4];
          float cim = ci[m], cjm = cj[m];
          float p0 = e1ia.x * e2ja.x * cim + e1ja.x * e2ia.x * cjm;
          float p1 = e1ia.y * e2ja.y * cim + e1ja.y * e2ia.y * cjm;
          float p2 = e1ia.z * e2ja.z * cim + e1ja.z * e2ia.z * cjm;
          float p3 = e1ia.w * e2ja.w * cim + e1ja.w * e2ia.w * cjm;
          float p4 = e1ib.x * e2jb.x * cim + e1jb.x * e2ib.x * cjm;
          float p5 = e1ib.y * e2jb.y * cim + e1jb.y * e2ib.y * cjm;
          float p6 = e1ib.z * e2jb.z * cim + e1jb.z * e2ib.z * cjm;
          float p7 = e1ib.w * e2jb.w * cim + e1jb.w * e2ib.w * cjm;
          af[m].q.x = packbf(p0, p1);
          af[m].q.y = packbf(p2, p3);
          af[m].q.z = packbf(p4, p5);
          af[m].q.w = packbf(p6, p7);
        } else {
          af[m].q = make_uint4(0, 0, 0, 0);
        }
      }
      const ushort* zb = zbh + ((size_t)ks << 14);  // ks*32*512
#pragma unroll
      for (int nf = 0; nf < 16; ++nf) {
        short8v bf = *(const short8v*)(zb + ((size_t)nf << 9));
        acc[0][nf] = __builtin_amdgcn_mfma_f32_16x16x32_bf16(af[0].v, bf,
                                                             acc[0][nf], 0, 0, 0);
        acc[1][nf] = __builtin_amdgcn_mfma_f32_16x16x32_bf16(af[1].v, bf,
                                                             acc[1][nf], 0, 0, 0);
      }
    }
  }
  // epilogue: C/D layout col=lane&15, row=quad*4+reg
#pragma unroll
  for (int nf = 0; nf < 16; ++nf) {
    int c = c0 + nf * 16 + frow;
    if (c >= DM) continue;
    float bb = 2.0f * b3[c];
#pragma unroll
    for (int m = 0; m < 2; ++m) {
      int bbase = b0 + wm * 32 + m * 16 + quad * 4;
#pragma unroll
      for (int r2 = 0; r2 < 4; ++r2) {
        int b = bbase + r2;
        if (b < NN) outS[(size_t)b * DM + c] = acc[m][nf][r2] + bb;
      }
    }
  }
}

// ---------------------------------------------------------------------------
// G: Q_sa via MFMA: T = relu(S@v1+b1); Q = T@v2 + b2. Barrier-free.
// 128 rows/block; A-frags from S (fp32->bf16 on the fly), B from V1B (global).
// ---------------------------------------------------------------------------
__global__ __launch_bounds__(256) void k_qsa2(
    const float* __restrict__ S, const ushort* __restrict__ V1B,
    const float* __restrict__ v1b, const float* __restrict__ v2w,
    const float* __restrict__ v2b, float* __restrict__ outQ) {
  int t = threadIdx.x;
  int b0 = blockIdx.x * 128;
  int lane = t & 63, wm = t >> 6;
  int frow = lane & 15, quad = lane >> 4;
  float4v acc[2][3];
#pragma unroll
  for (int m = 0; m < 2; ++m)
#pragma unroll
    for (int n = 0; n < 3; ++n) acc[m][n] = (float4v)(0.f);
  int gr[2]; bool gv[2];
#pragma unroll
  for (int m = 0; m < 2; ++m) {
    gr[m] = b0 + wm * 32 + m * 16 + frow;
    gv[m] = (gr[m] < NN);
  }
  for (int ks = 0; ks < 15; ++ks) {
    int kb = ks * 32 + quad * 8;
    bool kvalid = (kb + 8 <= DM);
    union { uint4 q; short8v v; } af[2];
#pragma unroll
    for (int m = 0; m < 2; ++m) {
      if (gv[m] && kvalid) {
        const float* sp = S + (size_t)gr[m] * DM + kb;
        float4 a = *(const float4*)sp;
        float4 b = *(const float4*)(sp + 4);
        af[m].q.x = packbf(a.x, a.y);
        af[m].q.y = packbf(a.z, a.w);
        af[m].q.z = packbf(b.x, b.y);
        af[m].q.w = packbf(b.z, b.w);
      } else {
        af[m].q = make_uint4(0, 0, 0, 0);
      }
    }
    const ushort* vb = V1B + ((size_t)(ks * 3) << 9) + lane * 8;
#pragma unroll
    for (int nf = 0; nf < 3; ++nf) {
      short8v bf = *(const short8v*)(vb + ((size_t)nf << 9));
      acc[0][nf] = __builtin_amdgcn_mfma_f32_16x16x32_bf16(af[0].v, bf,
                                                           acc[0][nf], 0, 0, 0);
      acc[1][nf] = __builtin_amdgcn_mfma_f32_16x16x32_bf16(af[1].v, bf,
                                                           acc[1][nf], 0, 0, 0);
    }
  }
  float b1c[3], v2c[3];
#pragma unroll
  for (int nf = 0; nf < 3; ++nf) {
    int c = nf * 16 + frow;
    b1c[nf] = v1b[c];
    v2c[nf] = v2w[c];
  }
  float qb = v2b[0];
#pragma unroll
  for (int m = 0; m < 2; ++m) {
#pragma unroll
    for (int r2 = 0; r2 < 4; ++r2) {
      float val = fmaxf(acc[m][0][r2] + b1c[0], 0.f) * v2c[0] +
                  fmaxf(acc[m][1][r2] + b1c[1], 0.f) * v2c[1] +
                  fmaxf(acc[m][2][r2] + b1c[2], 0.f) * v2c[2];
      val += __shfl_xor(val, 1);
      val += __shfl_xor(val, 2);
      val += __shfl_xor(val, 4);
      val += __shfl_xor(val, 8);
      if (frow == 0) {
        int row = b0 + wm * 32 + m * 16 + quad * 4 + r2;
        if (row < NN) outQ[row] = val + qb;
      }
    }
  }
}

// ---------------------------------------------------------------------------
extern "C" void kernel_launch(void* const* d_in, const int* in_sizes, int n_in,
                              void* d_out, int out_size, void* d_ws,
                              size_t ws_size, hipStream_t stream) {
  const float* x = (const float*)d_in[0];
  const float* label = (const float*)d_in[1];
  const float* h0 = (const float*)d_in[2];
  const float* w = (const float*)d_in[3];
  const float* dmat = (const float*)d_in[4];
  const float* l0w = (const float*)d_in[5];
  const float* l0b = (const float*)d_in[6];
  const float* l1w = (const float*)d_in[7];
  const float* l1b = (const float*)d_in[8];
  const float* l2w = (const float*)d_in[9];
  const float* l2b = (const float*)d_in[10];
  const float* l3w = (const float*)d_in[11];
  const float* l3b = (const float*)d_in[12];
  const float* l4w = (const float*)d_in[13];
  const float* l4b = (const float*)d_in[14];
  const float* l5w = (const float*)d_in[15];
  const float* l5b = (const float*)d_in[16];
  const float* w0 = (const float*)d_in[17];
  const float* b0v = (const float*)d_in[18];
  const float* w1 = (const float*)d_in[19];
  const float* b1v = (const float*)d_in[20];
  const float* w3 = (const float*)d_in[21];
  const float* b3 = (const float*)d_in[22];
  const float* v1w = (const float*)d_in[23];
  const float* v1b = (const float*)d_in[24];
  const float* v2w = (const float*)d_in[25];
  const float* v2b = (const float*)d_in[26];
  const int* remain_step = (const int*)d_in[29];

  float* ws = (float*)d_ws;
  float* base = ws + WS_BASE;
  float* h1 = ws + WS_H1;
  float* h2 = ws + WS_H2;
  float* hfull = ws + WS_HFULL;
  float* gmean = ws + WS_GMEAN;
  float* W0s = ws + WS_W0S;
  float* W1s = ws + WS_W1S;
  float* khf = ws + WS_KHF;
  float* vhf = ws + WS_VHF;
  float* B1 = ws + WS_B1;
  float* B2 = ws + WS_B2;
  float* SC1 = ws + WS_SC1;
  float* SC2 = ws + WS_SC2;
  float* Z = ws + WS_Z;
  ushort* ZB = (ushort*)(ws + WS_ZB);
  float* M1 = ws + WS_M1;
  float* M2 = ws + WS_M2;
  float* E1 = ws + WS_E1;
  float* E2 = ws + WS_E2;
  ushort* V1B = (ushort*)(ws + WS_V1B);
  float* SCL = ws + WS_B1;  // reuses B1/B2 slots after k_SC

  float* outS = (float*)d_out;
  float* outH = outS + OFF_H;
  float* outHF = outS + OFF_HF;
  float* outQ = outS + OFF_Q;

  k_base<<<NV, 256, 0, stream>>>(x, dmat, label, l0w, l0b, l1w, l1b, l2b, l3b,
                                 l4w, l4b, l5w, l5b, base);
  k_gcn<<<NV, 192, 0, stream>>>(h0, base, w, l2w, l3w, h1);
  k_gcn<<<NV, 192, 0, stream>>>(h1, base, w, l2w, l3w, h2);
  k_hfull<<<NV, 128, 0, stream>>>(h2, x, label, remain_step, hfull, outH, outHF);
  k_gmean<<<KG, 128, 0, stream>>>(hfull, gmean);
  k_wsum<<<(HD * DM + 255) / 256, 256, 0, stream>>>(w0, w1, W0s, W1s);
  k_kv<<<NV, 256, 0, stream>>>(hfull, W0s, b0v, W1s, b1v, khf, vhf);
  k_Z<<<dim3(NV, NH), 256, 0, stream>>>(vhf, w3, Z);
  k_ZB<<<(896 * 512 + 255) / 256, 256, 0, stream>>>(Z, ZB);
  k_v1B<<<(45 * 512 + 255) / 256, 256, 0, stream>>>(v1w, V1B);
  k_B<<<NV, 256, 0, stream>>>(hfull, gmean, w0, b0v, B1, B2);
  k_SC<<<NV, 256, 0, stream>>>(B1, B2, khf, SC1, SC2);
  k_rowmax<<<dim3(NV, NH), 64, 0, stream>>>(SC1, SC2, M1, M2);
  k_ml2<<<dim3(NV, NH), 256, 0, stream>>>(SC1, SC2, M1, M2, SCL);
  k_exp<<<dim3(NV, NH), 256, 0, stream>>>(SC1, SC2, M1, M2, E1, E2);
  k_sfused2<<<dim3(2, 313), 256, 0, stream>>>(E1, E2, SCL, ZB, b3, outS);
  k_qsa2<<<313, 256, 0, stream>>>(outS, V1B, v1b, v2w, v2b, outQ);
}